// Round 3
// baseline (318.266 us; speedup 1.0000x reference)
//
#include <hip/hip_runtime.h>
#include <hip/hip_bf16.h>

// CoarseGraining: y[i,b] = heg[b] * sum_j exp(-beta[j,b] * d2(i,j)) * wrho[j]
// N = M = 8192, NB = 16, WIDTH = 32. Inputs float32, output float32.
// R10 wave-per-i: 183us. R11 2 i's/wave: 155us. R12 j-split x2: 181us REGRESSION.
// R13 float2-packed math: 133us (VALUBusy 79%, HBM 0.3%, occ 31% grid-capped).
// R14 FAILED: fast-math folded magic-number range reduction.
// R15 poly exp2 + manual prefetch: 190us REGRESSION. Busy cycles UP 50%:
//   poly (~36cy/pair, main pipe) > hw exp pair (~30cy); trans ops execute ON
//   the main VALU (no co-issue). Model: v_exp_f32 ~12-13cy, pk ops 2cy,
//   R13 busy = 32*12.9 + 38*2 = 492cy/iter. Only lever: FEWER exps.
// R16: exploit Gaussian compactness + 100x absmax headroom (2.4e-4 vs 2.5e-2).
//   Morton counting-sort (4 bits/dim, 4096 bins, one-block LDS kernel) of both
//   j-sources and i-targets -> spatially compact j-tiles and i-pairs. Prep
//   stores per-plane max of bn. cg_pairs = exact R13 loop + wave-uniform
//   __all guards: skip 4-exp-pair plane when all lanes' best exponent <= -17
//   (log2) -> truncation error ~2e-3 worst case. Permutation is correctness-
//   safe for ANY bin quality (sum reorder only).
// Prediction: cg_pairs 70-125us (skip-fraction dependent; <=145 if no skips).

#define N_PTS 8192
#define M_PTS 8192
#define NBASIS 16
#define WIDTH 32
#define NBINS 4096

typedef float v2f __attribute__((ext_vector_type(2)));

__device__ __forceinline__ float exp2_hw(float x) { return __builtin_amdgcn_exp2f(x); }
__device__ __forceinline__ float log2_hw(float x) { return __builtin_amdgcn_logf(x); }

__device__ __forceinline__ float fast_tanh(float z) {
    float a = fabsf(z);
    float t = __expf(-2.0f * a);
    float r = (1.0f - t) / (1.0f + t);
    return copysignf(r, z);
}

__device__ __forceinline__ float log_cosh_f(float x) {
    float a = fabsf(x);
    return a + __logf(1.0f + __expf(-2.0f * a)) - 0.6931471805599453f;
}

// ---------------- Stage 0: Morton binning (counting sort) ----------------
// Block 0 sorts coords -> jperm; block 1 sorts out_coords -> iperm.
// 4 bits/dim (cell 3.0 units over +-24), 4096 bins, all in LDS.
// Output is a valid permutation regardless of binning quality.
__global__ __launch_bounds__(1024)
void cg_bin(const float* __restrict__ coords,
            const float* __restrict__ out_coords,
            unsigned* __restrict__ jperm,
            unsigned* __restrict__ iperm)
{
    const float* pts = (blockIdx.x == 0) ? coords : out_coords;
    unsigned* perm   = (blockIdx.x == 0) ? jperm : iperm;

    __shared__ unsigned short s_key[N_PTS];   // 16 KB
    __shared__ unsigned s_hist[NBINS];        // 16 KB
    __shared__ unsigned s_tmp[NBINS];         // 16 KB
    int t = threadIdx.x;

    for (int e = t; e < NBINS; e += 1024) s_hist[e] = 0;
    __syncthreads();

    for (int e = t; e < N_PTS; e += 1024) {
        float x = pts[e * 3 + 0];
        float y = pts[e * 3 + 1];
        float z = pts[e * 3 + 2];
        int xi = (int)((x + 24.0f) * 0.3333333f); xi = xi < 0 ? 0 : (xi > 15 ? 15 : xi);
        int yi = (int)((y + 24.0f) * 0.3333333f); yi = yi < 0 ? 0 : (yi > 15 ? 15 : yi);
        int zi = (int)((z + 24.0f) * 0.3333333f); zi = zi < 0 ? 0 : (zi > 15 ? 15 : zi);
        unsigned key = 0;
        #pragma unroll
        for (int k = 0; k < 4; ++k) {
            key |= ((unsigned)((xi >> k) & 1)) << (3 * k + 2);
            key |= ((unsigned)((yi >> k) & 1)) << (3 * k + 1);
            key |= ((unsigned)((zi >> k) & 1)) << (3 * k + 0);
        }
        s_key[e] = (unsigned short)key;
        atomicAdd(&s_hist[key], 1u);
    }
    __syncthreads();

    // inclusive Hillis-Steele scan over 4096, 12 ping-pong steps (ends in s_hist)
    #pragma unroll
    for (int step = 0; step < 12; ++step) {
        int d = 1 << step;
        unsigned* src = (step & 1) ? s_tmp : s_hist;
        unsigned* dst = (step & 1) ? s_hist : s_tmp;
        for (int e = t; e < NBINS; e += 1024)
            dst[e] = src[e] + (e >= d ? src[e - d] : 0u);
        __syncthreads();
    }
    // exclusive base: s_tmp[e] = inclusive[e-1]
    for (int e = t; e < NBINS; e += 1024)
        s_tmp[e] = (e == 0) ? 0u : s_hist[e - 1];
    __syncthreads();

    for (int e = t; e < N_PTS; e += 1024) {
        unsigned pos = atomicAdd(&s_tmp[s_key[e]], 1u);
        perm[pos] = (unsigned)e;
    }
}

// ---------------- Stage 1: per-source-point quantities (j-sorted) --------
// Thread k handles SORTED slot k, reading original index j = jperm[k].
// cw[k]        = (cx, cy, cz, wrho)
// bnq[q*N + k] = float4{ bn[4q..4q+3] }, bn = -log2(e)*beta  (<= 0)
// bmx[k]       = per-plane max of bn (least-negative exponent coefficient)
// hegf[0..15]  = log_cosh(embed(0))^1.5
__global__ __launch_bounds__(64)
void cg_prep(const float* __restrict__ rho,
             const float* __restrict__ gamma,
             const float* __restrict__ coords,
             const float* __restrict__ weights,
             const float* __restrict__ w1,
             const float* __restrict__ b1,
             const float* __restrict__ w2,
             const float* __restrict__ b2,
             const unsigned* __restrict__ jperm,
             float4* __restrict__ cw,
             float4* __restrict__ bnq,
             float4* __restrict__ bmx,
             float* __restrict__ hegf)
{
    const float PI_F = 3.14159265358979323846f;
    const float LOG2E = 1.4426950408889634f;

    __shared__ float s_w1[WIDTH], s_b1[WIDTH], s_w2[WIDTH * NBASIS], s_b2[NBASIS];
    int t = threadIdx.x;
    if (t < WIDTH) { s_w1[t] = w1[t]; s_b1[t] = b1[t]; }
    if (t < NBASIS) s_b2[t] = b2[t];
    #pragma unroll
    for (int k = 0; k < 8; ++k) s_w2[t + 64 * k] = w2[t + 64 * k];
    __syncthreads();

    int kdst = blockIdx.x * 64 + t;
    int j = (int)jperm[kdst];
    {
        float r = rho[j];
        float g = gamma[j];
        const float c83 = 38.28312007948569f;              // 4*(3*pi^2)^(2/3)
        float r83 = exp2_hw(2.6666666667f * log2_hw(r));   // r^(8/3)
        float s2 = g / (c83 * r83);
        float x = __logf(s2 + 1e-4f);

        float emb[NBASIS];
        #pragma unroll
        for (int b = 0; b < NBASIS; ++b) emb[b] = s_b2[b];
        #pragma unroll 4
        for (int w = 0; w < WIDTH; ++w) {
            float h = fast_tanh(fmaf(x, s_w1[w], s_b1[w]));
            #pragma unroll
            for (int b = 0; b < NBASIS; ++b)
                emb[b] = fmaf(h, s_w2[w * NBASIS + b], emb[b]);
        }
        float pref = PI_F * exp2_hw(0.6666666667f * log2_hw(0.5f * r));
        float scale = -LOG2E * pref;
        float pmax[4];
        #pragma unroll
        for (int q = 0; q < 4; ++q) {
            float b0 = scale * log_cosh_f(emb[4 * q + 0]);
            float b1v = scale * log_cosh_f(emb[4 * q + 1]);
            float b2v = scale * log_cosh_f(emb[4 * q + 2]);
            float b3 = scale * log_cosh_f(emb[4 * q + 3]);
            bnq[q * N_PTS + kdst] = make_float4(b0, b1v, b2v, b3);
            pmax[q] = fmaxf(fmaxf(b0, b1v), fmaxf(b2v, b3));
        }
        bmx[kdst] = make_float4(pmax[0], pmax[1], pmax[2], pmax[3]);

        cw[kdst] = make_float4(coords[j * 3 + 0],
                               coords[j * 3 + 1],
                               coords[j * 3 + 2],
                               weights[j] * r);
    }

    if (blockIdx.x == 0 && t == 0) {
        float emb0[NBASIS];
        #pragma unroll
        for (int b = 0; b < NBASIS; ++b) emb0[b] = s_b2[b];
        for (int w = 0; w < WIDTH; ++w) {
            float h = fast_tanh(s_b1[w]);   // x = 0
            #pragma unroll
            for (int b = 0; b < NBASIS; ++b)
                emb0[b] = fmaf(h, s_w2[w * NBASIS + b], emb0[b]);
        }
        #pragma unroll
        for (int b = 0; b < NBASIS; ++b) {
            float lc = fmaxf(log_cosh_f(emb0[b]), 0.0f);
            hegf[b] = lc * sqrtf(lc);       // lc^1.5
        }
    }
}

// ---------------- Stage 2: all-pairs, 2 i's/wave, tile/plane skip --------
// R13 structure (unroll 2, unconditional loads, hw exp everywhere) + wave-
// uniform skip guards. wave w owns spatially-adjacent i0=iperm[2w],
// i1=iperm[2w+1]; lane L handles sorted j = 64k+L (spatially compact tile).
// SKIP = -17 (log2): dropped terms <= e^-11.8 * wrho; worst-case sum ~2e-3.
__global__ __launch_bounds__(256, 4)
void cg_pairs(const float* __restrict__ oc,
              const float4* __restrict__ cw,
              const float4* __restrict__ bnq,
              const float4* __restrict__ bmx,
              const unsigned* __restrict__ iperm,
              const float* __restrict__ hegf,
              float* __restrict__ out)
{
    const float SKIP = -17.0f;
    int wave = (blockIdx.x << 2) | (threadIdx.x >> 6);
    int lane = threadIdx.x & 63;
    int i0 = (int)iperm[wave << 1];
    int i1 = (int)iperm[(wave << 1) | 1];

    v2f oxv = { oc[i0 * 3 + 0], oc[i1 * 3 + 0] };
    v2f oyv = { oc[i0 * 3 + 1], oc[i1 * 3 + 1] };
    v2f ozv = { oc[i0 * 3 + 2], oc[i1 * 3 + 2] };

    v2f acc[NBASIS];
    #pragma unroll
    for (int b = 0; b < NBASIS; ++b) acc[b] = (v2f)0.0f;

    #pragma unroll 2
    for (int k = 0; k < N_PTS / 64; ++k) {
        int j = (k << 6) | lane;                 // lane-consecutive: coalesced
        float4 c = cw[j];
        float4 bm = bmx[j];
        v2f dx = oxv - c.x;
        v2f dy = oyv - c.y;
        v2f dz = ozv - c.z;
        v2f d2 = dx * dx + dy * dy + dz * dz;
        // loads stay unconditional so the scheduler can hoist next-iter loads
        float4 B0 = bnq[0 * N_PTS + j];
        float4 B1 = bnq[1 * N_PTS + j];
        float4 B2 = bnq[2 * N_PTS + j];
        float4 B3 = bnq[3 * N_PTS + j];
        float bmw = fmaxf(fmaxf(bm.x, bm.y), fmaxf(bm.z, bm.w));
        v2f pw = bmw * d2;
        if (!__all((pw.x <= SKIP) && (pw.y <= SKIP))) {
            v2f w = (v2f)c.w;
            v2f pm;
            pm = bm.x * d2;
            if (!__all((pm.x <= SKIP) && (pm.y <= SKIP))) {
                v2f p0 = B0.x * d2, p1 = B0.y * d2, p2 = B0.z * d2, p3 = B0.w * d2;
                v2f e0 = { exp2_hw(p0.x), exp2_hw(p0.y) };
                v2f e1 = { exp2_hw(p1.x), exp2_hw(p1.y) };
                v2f e2 = { exp2_hw(p2.x), exp2_hw(p2.y) };
                v2f e3 = { exp2_hw(p3.x), exp2_hw(p3.y) };
                acc[0] += e0 * w; acc[1] += e1 * w; acc[2] += e2 * w; acc[3] += e3 * w;
            }
            pm = bm.y * d2;
            if (!__all((pm.x <= SKIP) && (pm.y <= SKIP))) {
                v2f p0 = B1.x * d2, p1 = B1.y * d2, p2 = B1.z * d2, p3 = B1.w * d2;
                v2f e0 = { exp2_hw(p0.x), exp2_hw(p0.y) };
                v2f e1 = { exp2_hw(p1.x), exp2_hw(p1.y) };
                v2f e2 = { exp2_hw(p2.x), exp2_hw(p2.y) };
                v2f e3 = { exp2_hw(p3.x), exp2_hw(p3.y) };
                acc[4] += e0 * w; acc[5] += e1 * w; acc[6] += e2 * w; acc[7] += e3 * w;
            }
            pm = bm.z * d2;
            if (!__all((pm.x <= SKIP) && (pm.y <= SKIP))) {
                v2f p0 = B2.x * d2, p1 = B2.y * d2, p2 = B2.z * d2, p3 = B2.w * d2;
                v2f e0 = { exp2_hw(p0.x), exp2_hw(p0.y) };
                v2f e1 = { exp2_hw(p1.x), exp2_hw(p1.y) };
                v2f e2 = { exp2_hw(p2.x), exp2_hw(p2.y) };
                v2f e3 = { exp2_hw(p3.x), exp2_hw(p3.y) };
                acc[8] += e0 * w; acc[9] += e1 * w; acc[10] += e2 * w; acc[11] += e3 * w;
            }
            pm = bm.w * d2;
            if (!__all((pm.x <= SKIP) && (pm.y <= SKIP))) {
                v2f p0 = B3.x * d2, p1 = B3.y * d2, p2 = B3.z * d2, p3 = B3.w * d2;
                v2f e0 = { exp2_hw(p0.x), exp2_hw(p0.y) };
                v2f e1 = { exp2_hw(p1.x), exp2_hw(p1.y) };
                v2f e2 = { exp2_hw(p2.x), exp2_hw(p2.y) };
                v2f e3 = { exp2_hw(p3.x), exp2_hw(p3.y) };
                acc[12] += e0 * w; acc[13] += e1 * w; acc[14] += e2 * w; acc[15] += e3 * w;
            }
        }
    }

    // 6-step butterfly over 64 lanes, 16 v2f values
    #pragma unroll
    for (int m = 1; m < 64; m <<= 1) {
        #pragma unroll
        for (int b = 0; b < NBASIS; ++b) {
            v2f other = { __shfl_xor(acc[b].x, m, 64),
                          __shfl_xor(acc[b].y, m, 64) };
            acc[b] += other;
        }
    }

    if (lane == 0) {
        float4* o0 = (float4*)(out + i0 * NBASIS);
        float4* o1 = (float4*)(out + i1 * NBASIS);
        #pragma unroll
        for (int q = 0; q < 4; ++q) {
            float h0 = hegf[4 * q + 0];
            float h1 = hegf[4 * q + 1];
            float h2 = hegf[4 * q + 2];
            float h3 = hegf[4 * q + 3];
            o0[q] = make_float4(acc[4 * q + 0].x * h0, acc[4 * q + 1].x * h1,
                                acc[4 * q + 2].x * h2, acc[4 * q + 3].x * h3);
            o1[q] = make_float4(acc[4 * q + 0].y * h0, acc[4 * q + 1].y * h1,
                                acc[4 * q + 2].y * h2, acc[4 * q + 3].y * h3);
        }
    }
}

extern "C" void kernel_launch(void* const* d_in, const int* in_sizes, int n_in,
                              void* d_out, int out_size, void* d_ws, size_t ws_size,
                              hipStream_t stream) {
    const float* rho        = (const float*)d_in[0];
    const float* gamma      = (const float*)d_in[1];
    const float* coords     = (const float*)d_in[2];
    const float* weights    = (const float*)d_in[3];
    const float* out_coords = (const float*)d_in[4];
    const float* w1         = (const float*)d_in[5];
    const float* b1         = (const float*)d_in[6];
    const float* w2         = (const float*)d_in[7];
    const float* b2         = (const float*)d_in[8];

    char* ws = (char*)d_ws;
    // ws layout (~836 KiB):
    //   cw    : N * float4              = 128 KiB  @ 0
    //   bnq   : 4 planes * N * float4   = 512 KiB  @ 128K
    //   bmx   : N * float4              = 128 KiB  @ 640K
    //   hegf  : 16 * float              = 64 B     @ 768K
    //   jperm : N * u32                 = 32 KiB   @ 772K
    //   iperm : M * u32                 = 32 KiB   @ 804K
    float4*   cw    = (float4*)(ws);
    float4*   bnq   = (float4*)(ws + (128 << 10));
    float4*   bmx   = (float4*)(ws + (640 << 10));
    float*    hegf  = (float*)  (ws + (768 << 10));
    unsigned* jperm = (unsigned*)(ws + (772 << 10));
    unsigned* iperm = (unsigned*)(ws + (804 << 10));

    cg_bin<<<2, 1024, 0, stream>>>(coords, out_coords, jperm, iperm);

    cg_prep<<<N_PTS / 64, 64, 0, stream>>>(rho, gamma, coords, weights,
                                           w1, b1, w2, b2, jperm,
                                           cw, bnq, bmx, hegf);

    cg_pairs<<<M_PTS / 8, 256, 0, stream>>>(out_coords, cw, bnq, bmx, iperm,
                                            hegf, (float*)d_out);
}

// Round 4
// 218.957 us; speedup vs baseline: 1.4536x; 1.4536x over previous
//
#include <hip/hip_runtime.h>
#include <hip/hip_bf16.h>

// CoarseGraining: y[i,b] = heg[b] * sum_j exp(-beta[j,b] * d2(i,j)) * wrho[j]
// N = M = 8192, NB = 16, WIDTH = 32. Inputs float32, output float32.
// R10 wave-per-i: 183us. R11 2 i's/wave: 155us. R12 j-split x2 (separate
//   blocks): 181us REGRESSION -- VGPR hit exactly 64 = occupancy-halving
//   boundary, so no TLP gain + reduction overhead.
// R13 float2-packed math: 133us (VALUBusy 79%, HBM 0.3%, occ 31% grid-capped).
// R14 FAILED: fast-math folded magic-number range reduction.
// R15 poly exp2 on main pipe: 190us REGRESSION (poly issue-cycles > hw exp;
//   trans executes ON the VALU, no co-issue). Model: exp ~13cy, pk 2cy,
//   busy = 32*13 + 38*2 = 492cy/iter, 21% idle.
// R16 Morton sort + wave-uniform skip guards: 258us REGRESSION. Guards never
//   fire (each plane has a small-beta basis -> bn_max ~ 0; absmax bit-equal
//   to R13) and branches destroyed the unroll-2 pipeline. Reverted.
// R17: attack the 21% idle with real TLP. 512-thread blocks, 8 waves: wave
//   pair (2t,2t+1) shares i-pair 4*blk+t, each does one 4096-j half. 8192
//   waves -> 8/SIMD resident (launch_bounds(512,8); VGPR must stay <=63,
//   R13 body is 60). Combine: butterfly all-reduce -> lanes 0-15 hold sums,
//   half-1 wave writes v2f to LDS, syncthreads, half-0 wave adds + stores
//   with hegf. Inner loop bit-identical to R13.
// Prediction: cg_pairs 105-115us (VALUBusy ~90, Occupancy ~55-60); if flat
//   at ~130 with occ ~60 -> exp issue-occupancy is the roofline.

#define N_PTS 8192
#define M_PTS 8192
#define NBASIS 16
#define WIDTH 32

typedef float v2f __attribute__((ext_vector_type(2)));

__device__ __forceinline__ float exp2_hw(float x) { return __builtin_amdgcn_exp2f(x); }
__device__ __forceinline__ float log2_hw(float x) { return __builtin_amdgcn_logf(x); }

__device__ __forceinline__ float fast_tanh(float z) {
    float a = fabsf(z);
    float t = __expf(-2.0f * a);
    float r = (1.0f - t) / (1.0f + t);
    return copysignf(r, z);
}

__device__ __forceinline__ float log_cosh_f(float x) {
    float a = fabsf(x);
    return a + __logf(1.0f + __expf(-2.0f * a)) - 0.6931471805599453f;
}

// ---------------- Stage 1: per-source-point quantities ----------------
// cw[j]        = (cx, cy, cz, wrho)
// bnq[q*N + j] = float4{ bn[j][4q..4q+3] }, bn = -log2(e)*beta (q-plane layout)
// hegf[0..15]  = log_cosh(embed(0))^1.5
__global__ __launch_bounds__(64)
void cg_prep(const float* __restrict__ rho,
             const float* __restrict__ gamma,
             const float* __restrict__ coords,
             const float* __restrict__ weights,
             const float* __restrict__ w1,
             const float* __restrict__ b1,
             const float* __restrict__ w2,
             const float* __restrict__ b2,
             float4* __restrict__ cw,
             float4* __restrict__ bnq,
             float* __restrict__ hegf)
{
    const float PI_F = 3.14159265358979323846f;
    const float LOG2E = 1.4426950408889634f;

    __shared__ float s_w1[WIDTH], s_b1[WIDTH], s_w2[WIDTH * NBASIS], s_b2[NBASIS];
    int t = threadIdx.x;
    if (t < WIDTH) { s_w1[t] = w1[t]; s_b1[t] = b1[t]; }
    if (t < NBASIS) s_b2[t] = b2[t];
    #pragma unroll
    for (int k = 0; k < 8; ++k) s_w2[t + 64 * k] = w2[t + 64 * k];
    __syncthreads();

    int j = blockIdx.x * 64 + t;
    {
        float r = rho[j];
        float g = gamma[j];
        const float c83 = 38.28312007948569f;              // 4*(3*pi^2)^(2/3)
        float r83 = exp2_hw(2.6666666667f * log2_hw(r));   // r^(8/3)
        float s2 = g / (c83 * r83);
        float x = __logf(s2 + 1e-4f);

        float emb[NBASIS];
        #pragma unroll
        for (int b = 0; b < NBASIS; ++b) emb[b] = s_b2[b];
        #pragma unroll 4
        for (int w = 0; w < WIDTH; ++w) {
            float h = fast_tanh(fmaf(x, s_w1[w], s_b1[w]));
            #pragma unroll
            for (int b = 0; b < NBASIS; ++b)
                emb[b] = fmaf(h, s_w2[w * NBASIS + b], emb[b]);
        }
        float pref = PI_F * exp2_hw(0.6666666667f * log2_hw(0.5f * r));
        float scale = -LOG2E * pref;
        #pragma unroll
        for (int q = 0; q < 4; ++q) {
            bnq[q * N_PTS + j] = make_float4(scale * log_cosh_f(emb[4 * q + 0]),
                                             scale * log_cosh_f(emb[4 * q + 1]),
                                             scale * log_cosh_f(emb[4 * q + 2]),
                                             scale * log_cosh_f(emb[4 * q + 3]));
        }

        cw[j] = make_float4(coords[j * 3 + 0],
                            coords[j * 3 + 1],
                            coords[j * 3 + 2],
                            weights[j] * r);
    }

    if (blockIdx.x == 0 && t == 0) {
        float emb0[NBASIS];
        #pragma unroll
        for (int b = 0; b < NBASIS; ++b) emb0[b] = s_b2[b];
        for (int w = 0; w < WIDTH; ++w) {
            float h = fast_tanh(s_b1[w]);   // x = 0
            #pragma unroll
            for (int b = 0; b < NBASIS; ++b)
                emb0[b] = fmaf(h, s_w2[w * NBASIS + b], emb0[b]);
        }
        #pragma unroll
        for (int b = 0; b < NBASIS; ++b) {
            float lc = fmaxf(log_cosh_f(emb0[b]), 0.0f);
            hegf[b] = lc * sqrtf(lc);       // lc^1.5
        }
    }
}

// ---------------- Stage 2: all-pairs, 2 i's/wave, j-split x2 in-block ----
// 1024 blocks x 512 threads (8 waves). Wave pair (2t, 2t+1) shares i-pair
// 4*blk+t; wave 2t does j in [0,4096), wave 2t+1 does [4096,8192). 8192
// waves total -> 8 waves/SIMD resident. Inner loop = R13 exactly.
__global__ __launch_bounds__(512, 8)
void cg_pairs(const float* __restrict__ oc,
              const float4* __restrict__ cw,
              const float4* __restrict__ bnq,
              const float* __restrict__ hegf,
              float* __restrict__ out)
{
    __shared__ v2f s_acc[4][NBASIS];   // partials from half-1 waves (512 B)

    int wib  = threadIdx.x >> 6;       // wave in block: 0..7
    int t    = wib >> 1;               // i-pair slot: 0..3
    int half = wib & 1;                // j-half
    int lane = threadIdx.x & 63;
    int pair = (blockIdx.x << 2) | t;
    int i0 = pair << 1;
    int i1 = i0 | 1;

    v2f oxv = { oc[i0 * 3 + 0], oc[i1 * 3 + 0] };
    v2f oyv = { oc[i0 * 3 + 1], oc[i1 * 3 + 1] };
    v2f ozv = { oc[i0 * 3 + 2], oc[i1 * 3 + 2] };

    v2f acc[NBASIS];
    #pragma unroll
    for (int b = 0; b < NBASIS; ++b) acc[b] = (v2f)0.0f;

    int jbase = half << 12;            // 0 or 4096

    #pragma unroll 2
    for (int k = 0; k < N_PTS / 128; ++k) {      // 64 iters per wave
        int j = jbase + (k << 6) + lane;         // lane-consecutive: coalesced
        float4 c = cw[j];
        v2f dx = oxv - c.x;                      // pk_add (scalar broadcast)
        v2f dy = oyv - c.y;
        v2f dz = ozv - c.z;
        v2f d2 = dx * dx + dy * dy + dz * dz;    // pk_mul + 2x pk_fma
        #pragma unroll
        for (int q = 0; q < 4; ++q) {
            float4 b4 = bnq[q * N_PTS + j];      // coalesced dwordx4
            v2f p0 = b4.x * d2;                  // pk_mul
            v2f p1 = b4.y * d2;
            v2f p2 = b4.z * d2;
            v2f p3 = b4.w * d2;
            v2f e0 = { exp2_hw(p0.x), exp2_hw(p0.y) };
            v2f e1 = { exp2_hw(p1.x), exp2_hw(p1.y) };
            v2f e2 = { exp2_hw(p2.x), exp2_hw(p2.y) };
            v2f e3 = { exp2_hw(p3.x), exp2_hw(p3.y) };
            acc[q * 4 + 0] += e0 * c.w;          // pk_fma
            acc[q * 4 + 1] += e1 * c.w;
            acc[q * 4 + 2] += e2 * c.w;
            acc[q * 4 + 3] += e3 * c.w;
        }
    }

    // 6-step butterfly all-reduce over 64 lanes, 16 v2f values
    #pragma unroll
    for (int m = 1; m < 64; m <<= 1) {
        #pragma unroll
        for (int b = 0; b < NBASIS; ++b) {
            v2f other = { __shfl_xor(acc[b].x, m, 64),
                          __shfl_xor(acc[b].y, m, 64) };
            acc[b] += other;
        }
    }

    // combine the two j-halves via LDS, then store with hegf fused
    if (half == 1 && lane < NBASIS) s_acc[t][lane] = acc[lane];
    __syncthreads();
    if (half == 0 && lane < NBASIS) {
        v2f tot = acc[lane] + s_acc[t][lane];
        float h = hegf[lane];
        out[i0 * NBASIS + lane] = tot.x * h;
        out[i1 * NBASIS + lane] = tot.y * h;
    }
}

extern "C" void kernel_launch(void* const* d_in, const int* in_sizes, int n_in,
                              void* d_out, int out_size, void* d_ws, size_t ws_size,
                              hipStream_t stream) {
    const float* rho        = (const float*)d_in[0];
    const float* gamma      = (const float*)d_in[1];
    const float* coords     = (const float*)d_in[2];
    const float* weights    = (const float*)d_in[3];
    const float* out_coords = (const float*)d_in[4];
    const float* w1         = (const float*)d_in[5];
    const float* b1         = (const float*)d_in[6];
    const float* w2         = (const float*)d_in[7];
    const float* b2         = (const float*)d_in[8];

    char* ws = (char*)d_ws;
    // ws layout (640 KiB + 64 B):
    //   cw   : N * float4              = 128 KiB  @ 0
    //   bnq  : 4 planes * N * float4   = 512 KiB  @ 128K
    //   hegf : 16 * float                          @ 640K
    float4* cw   = (float4*)(ws);
    float4* bnq  = (float4*)(ws + (128 << 10));
    float*  hegf = (float*) (ws + (640 << 10));

    cg_prep<<<N_PTS / 64, 64, 0, stream>>>(rho, gamma, coords, weights,
                                           w1, b1, w2, b2,
                                           cw, bnq, hegf);

    cg_pairs<<<M_PTS / 8, 512, 0, stream>>>(out_coords, cw, bnq, hegf,
                                            (float*)d_out);
}